// Round 8
// baseline (191.153 us; speedup 1.0000x reference)
//
#include <hip/hip_runtime.h>
#include <cfloat>
#include <stdint.h>

#define B_   16
#define N_   2048
#define KK   10          // window = K+1
#define H_   128
#define SUB  16          // chunk size
#define NCH  (N_ / SUB)  // 128 chunks

__device__ inline uint32_t f32_ordered(float f) {
    uint32_t u = __float_as_uint(f);
    return (u & 0x80000000u) ? ~u : (u | 0x80000000u);
}

// ---- fused setup: blocks 0..15 bitonic-sort one batch each by x;
//      blocks 16..18 precompute weff/btot.
__global__ __launch_bounds__(1024) void setup_kernel(
    const float* __restrict__ x,
    const float* __restrict__ Wconv, const float* __restrict__ bconv,
    const float* __restrict__ b1,    const float* __restrict__ W2,
    const float* __restrict__ b2,
    float4* __restrict__ xsorted,    // [B][N] (px,py,sm,orig_idx_bits)
    float*  __restrict__ weff,       // [H*20]
    float*  __restrict__ btot)       // [H]
{
#pragma clang fp contract(off)
    __shared__ uint64_t sk[N_];
    const int tid = threadIdx.x;
    if (blockIdx.x >= 16) {
        int gid = (blockIdx.x - 16) * 1024 + tid;
        if (gid < H_ * KK * 2) {
            int e = gid / 20, r = gid % 20, k = r >> 1, c = r & 1;
            float acc = 0.f;
            for (int h = 0; h < H_; ++h)
                acc += W2[e * H_ + h] * Wconv[h * (2 * KK) + c * KK + k];
            weff[gid] = acc;
        } else if (gid < H_ * KK * 2 + H_) {
            int e = gid - H_ * KK * 2;
            float acc = b1[e] + b2[e];
            for (int h = 0; h < H_; ++h) acc += W2[e * H_ + h] * bconv[h];
            btot[e] = acc;
        }
        return;
    }
    const int b = blockIdx.x;
    const float2* xb = (const float2*)(x + (size_t)b * N_ * 2);
    for (int i = tid; i < N_; i += 1024)
        sk[i] = ((uint64_t)f32_ordered(xb[i].x) << 32) | (uint32_t)i;
    __syncthreads();
    for (int size = 2; size <= N_; size <<= 1) {
        for (int stride = size >> 1; stride > 0; stride >>= 1) {
            int i = 2 * tid - (tid & (stride - 1));
            int j = i + stride;
            bool up = ((i & size) == 0);
            uint64_t a = sk[i], c = sk[j];
            if (up ? (a > c) : (a < c)) { sk[i] = c; sk[j] = a; }
            __syncthreads();
        }
    }
    for (int i = tid; i < N_; i += 1024) {
        uint32_t idx = (uint32_t)sk[i];
        float2 p = xb[idx];
        float sm = p.x * p.x + p.y * p.y;      // no FMA (np sum convention)
        xsorted[(size_t)b * N_ + i] = make_float4(p.x, p.y, sm, __uint_as_float(idx));
    }
}

// KINIT: d2-field = +inf (so the f32 guard passes while unfilled), rest 1s.
#define KINIT ((((uint64_t)0x7F800000u) << 32) | 0xFFFFFFFFull)

// ---- main kernel: 512 threads; lane = 8*qi + ri. Each lane: private top-10
// for query qi over chunks == ri (mod 8). Per-query frozen bound after seed;
// per-lane two-pointer expansion; in-register octet merge via shfl.
__global__ __launch_bounds__(512, 4) void knn_conv_kernel(
    const float4* __restrict__ xsorted,
    const float* __restrict__ W1,
    const float* __restrict__ weff,
    const float* __restrict__ btot,
    float* __restrict__ out)
{
#pragma clang fp contract(off)
    __shared__ float4 xs4[N_];          // 32 KB
    __shared__ float  wcoord[64 * 21];  //  5.25 KB

    const int tid  = threadIdx.x;
    const int qi   = tid >> 3;          // query 0..63 (8 lanes each, same wave)
    const int ri   = tid & 7;           // candidate-range id
    const int b    = blockIdx.x >> 5;
    const int tile = blockIdx.x & 31;

    const float4* xb = xsorted + (size_t)b * N_;
    for (int i = tid; i < N_; i += 512) xs4[i] = xb[i];
    __syncthreads();

    const int    n  = tile * 64 + qi;
    const float4 qv = xs4[n];
    const float  qx = qv.x, qy = qv.y, sqn = qv.z;

    uint64_t hk[KK];
#pragma unroll
    for (int j = 0; j < KK; ++j) hk[j] = KINIT;
    float h9f = __uint_as_float(0x7F800000u);   // +inf

    // scan one 16-candidate chunk, updating the private sorted-10
    auto scan16 = [&](int c) {
        const int base = c << 4;
        for (int mm = 0; mm < SUB; ++mm) {
            float4 c4 = xs4[base + mm];
            float s  = sqn + c4.z;
            float pr = qx * c4.x;                        // rn(qx*px)
            float dt = __builtin_fmaf(qy, c4.y, pr);     // fma accumulate (np)
            float d2 = __builtin_fmaf(-2.0f, dt, s);     // rn(s - 2*dot)
            float dc = d2 > 0.0f ? d2 : 0.0f;
            if (dc <= h9f) {
                uint32_t oi = __float_as_uint(c4.w);
                uint64_t key = ((uint64_t)__float_as_uint(dc) << 32)
                             | (oi << 11) | (uint32_t)(base + mm);
                if (key < hk[KK - 1]) {
#pragma unroll
                    for (int j = KK - 1; j >= 1; --j) {
                        bool cj  = key < hk[j];
                        bool cjm = key < hk[j - 1];
                        hk[j] = cj ? (cjm ? hk[j - 1] : key) : hk[j];
                    }
                    hk[0] = (key < hk[0]) ? key : hk[0];
                    h9f = __uint_as_float((uint32_t)(hk[KK - 1] >> 32));
                }
            }
        }
    };

    // seed: nearest owned chunk (== ri mod 8) to tile's chunk range [T0,T0+3]
    const int T0 = 4 * tile;
    int cb_ = T0 + ((ri - T0) & 7);
    int ca_ = cb_ - 8;
    int cn;
    if (cb_ <= T0 + 3) cn = cb_;
    else cn = ((T0 - ca_) < (cb_ - (T0 + 3))) ? ca_ : cb_;
    if (cn < 0)    cn = cb_;
    if (cn >= NCH) cn = ca_;
    scan16(cn);

    // frozen per-query bound: min over the 8 ri-lanes of private 10th-best.
    // Sound: 10th-of-subset >= merged 10th. Margin 1e-7 >> 2.4e-9 f32 d2 err.
    float qb = h9f;
    qb = fminf(qb, __shfl_xor(qb, 1, 64));
    qb = fminf(qb, __shfl_xor(qb, 2, 64));
    qb = fminf(qb, __shfl_xor(qb, 4, 64));
    const float qbm = qb + 1e-7f;

    // per-lane outward expansion over owned chunks (divergence OK; no
    // cross-lane ops inside). Gap monotone per side -> break is sound.
    for (int c = cn - 8; c >= 0; c -= 8) {
        float gap = qx - xs4[(c << 4) + 15].x;          // >= 0 (sorted)
        if (gap * gap > qbm) break;
        scan16(c);
    }
    for (int c = cn + 8; c < NCH; c += 8) {
        float gap = fmaxf(0.0f, xs4[c << 4].x - qx);    // clamp: c may overlap tile
        if (gap * gap > qbm) break;
        scan16(c);
    }

    // hoist epilogue weights (global, L2-hot) before the barrier
    const int e = tid & 127;
    float we[20];
    {
        const float4* wp = (const float4*)(weff + e * 20);
#pragma unroll
        for (int r = 0; r < 5; ++r) {
            float4 v = wp[r];
            we[4 * r + 0] = v.x; we[4 * r + 1] = v.y;
            we[4 * r + 2] = v.z; we[4 * r + 3] = v.w;
        }
    }
    const float w1x = W1[e * 2 + 0];
    const float w1y = W1[e * 2 + 1];
    const float bt  = btot[e];

    // octet merge: 10x extract-min over the 8 lanes' sorted lists via shfl.
    // Keys unique (pos field) -> exactly one winner per step.
#pragma unroll
    for (int sel = 0; sel < KK; ++sel) {
        uint64_t v = hk[0], t;
        t = __shfl_xor((unsigned long long)v, 1, 64); v = (t < v) ? t : v;
        t = __shfl_xor((unsigned long long)v, 2, 64); v = (t < v) ? t : v;
        t = __shfl_xor((unsigned long long)v, 4, 64); v = (t < v) ? t : v;
        if (ri == (sel & 7)) {                 // designated writer (any lane ok)
            float4 c = xs4[(int)(v & 0x7FF)];
            const int k = (KK - 1) - sel;      // flip: nearest -> k=9
            wcoord[qi * 21 + 2 * k + 0] = c.x;
            wcoord[qi * 21 + 2 * k + 1] = c.y;
        }
        if (hk[0] == v) {                      // winner pops its head
#pragma unroll
            for (int j = 0; j < KK - 1; ++j) hk[j] = hk[j + 1];
            hk[KK - 1] = KINIT;
        }
    }
    __syncthreads();

    // epilogue: thread -> channel e; rows scattered to ORIGINAL indices
    // (128 consecutive floats per row, coalesced per wave-store).
    const int qb_ = tid >> 7;
    const size_t obase = (size_t)b * N_ * H_;
#pragma unroll
    for (int jj = 0; jj < 16; ++jj) {
        const int qq = qb_ + 4 * jj;
        float4 xq = xs4[tile * 64 + qq];
        uint32_t orig = __float_as_uint(xq.w);
        const float* wc = &wcoord[qq * 21];
        float acc = bt;
        acc += xq.x * w1x;
        acc += xq.y * w1y;
#pragma unroll
        for (int k = 0; k < KK; ++k) {
            acc += wc[2 * k + 0] * we[2 * k + 0];
            acc += wc[2 * k + 1] * we[2 * k + 1];
        }
        out[obase + (size_t)orig * H_ + e] = acc;
    }
}

extern "C" void kernel_launch(void* const* d_in, const int* in_sizes, int n_in,
                              void* d_out, int out_size, void* d_ws, size_t ws_size,
                              hipStream_t stream) {
    const float* x     = (const float*)d_in[0];
    const float* Wconv = (const float*)d_in[1];
    const float* bconv = (const float*)d_in[2];
    const float* W1    = (const float*)d_in[3];
    const float* b1    = (const float*)d_in[4];
    const float* W2    = (const float*)d_in[5];
    const float* b2    = (const float*)d_in[6];
    float* out  = (float*)d_out;
    float* weff = (float*)d_ws;                           // 2560 floats
    float* btot = weff + H_ * KK * 2;                     // 128 floats
    float4* xsorted = (float4*)((char*)d_ws + 16384);     // 16*2048*16B

    setup_kernel<<<dim3(19), dim3(1024), 0, stream>>>(
        x, Wconv, bconv, b1, W2, b2, xsorted, weff, btot);
    knn_conv_kernel<<<dim3(B_ * (N_ / 64)), dim3(512), 0, stream>>>(
        xsorted, W1, weff, btot, out);
}